// Round 1
// baseline (815.828 us; speedup 1.0000x reference)
//
#include <hip/hip_runtime.h>
#include <hip/hip_bf16.h>
#include <cstdint>
#include <cstddef>

// Problem constants
#define T_DIM   2048
#define HID     4096
#define HQ      32
#define HKV     8
#define D_HEAD  128
#define QKV_N   6144   // 4096 Q + 1024 K + 1024 V
#define KOFF    4096
#define VOFF    5120

typedef __attribute__((ext_vector_type(8))) short short8;   // 8 bf16 (4 VGPRs)
typedef __attribute__((ext_vector_type(4))) float floatx4;  // MFMA C/D frag

__device__ __forceinline__ ushort f2bf(float f) {
    union { float f; uint u; } v; v.f = f;
    uint r = v.u + 0x7fffu + ((v.u >> 16) & 1u);  // RNE
    return (ushort)(r >> 16);
}
__device__ __forceinline__ float bf2f(ushort h) {
    union { uint u; float f; } v; v.u = ((uint)h) << 16; return v.f;
}
// 8 bf16 from 8B-aligned LDS
__device__ __forceinline__ short8 ld8(const ushort* p) {
    uint2 a = *(const uint2*)p, b = *(const uint2*)(p + 4);
    union { uint u[4]; short8 s; } x;
    x.u[0] = a.x; x.u[1] = a.y; x.u[2] = b.x; x.u[3] = b.y;
    return x.s;
}
// 8 bf16 from 4B-aligned LDS
__device__ __forceinline__ short8 ld8_4(const ushort* p) {
    union { uint u[4]; short8 s; } x;
    x.u[0] = *(const uint*)(p);
    x.u[1] = *(const uint*)(p + 2);
    x.u[2] = *(const uint*)(p + 4);
    x.u[3] = *(const uint*)(p + 6);
    return x.s;
}

// ---------------- elementwise cast fp32 -> bf16 ----------------
__global__ void cast_f32_bf16(const float* __restrict__ in, ushort* __restrict__ out, int n) {
    int i = (blockIdx.x * blockDim.x + threadIdx.x) * 4;
    if (i < n) {
        float4 v = *(const float4*)(in + i);
        ushort4 o;
        o.x = f2bf(v.x); o.y = f2bf(v.y); o.z = f2bf(v.z); o.w = f2bf(v.w);
        *(ushort4*)(out + i) = o;
    }
}

// ---------------- transpose + cast: W[K][N] fp32 -> Wt[N][K] bf16 ----------------
__global__ void transpose_cast(const float* __restrict__ W, ushort* __restrict__ Wt, int K, int N) {
    __shared__ float tile[32][33];
    int n0 = blockIdx.x * 32, k0 = blockIdx.y * 32;
    int tx = threadIdx.x & 31, ty = threadIdx.x >> 5;  // 32 x 8
#pragma unroll
    for (int i = 0; i < 4; i++) {
        int r = ty + i * 8;
        tile[r][tx] = W[(size_t)(k0 + r) * N + n0 + tx];
    }
    __syncthreads();
#pragma unroll
    for (int i = 0; i < 4; i++) {
        int r = ty + i * 8;
        Wt[(size_t)(n0 + r) * K + k0 + tx] = f2bf(tile[tx][r]);
    }
}

// ---------------- bf16 MFMA GEMM: C[M][N] = A[M][K] * Bt[N][K]^T ----------------
// 128x128 tile, 4 waves (2x2 of 64x64), 16x16x32 MFMA, BK=32. OutT = ushort(bf16) or float.
template <typename OutT>
__global__ __launch_bounds__(256) void gemm_bt(const ushort* __restrict__ A,
                                               const ushort* __restrict__ Bt,
                                               OutT* __restrict__ C,
                                               int K, int lda, int ldb, int ldc) {
    __shared__ ushort As[128 * 32];
    __shared__ ushort Bs[128 * 32];
    int tid = threadIdx.x;
    int w = tid >> 6, lane = tid & 63, quad = lane >> 4, l15 = lane & 15;
    int wr = (w >> 1) * 64, wc = (w & 1) * 64;
    int m0 = blockIdx.y * 128, n0 = blockIdx.x * 128;

    floatx4 acc[4][4];
    floatx4 z = {0.f, 0.f, 0.f, 0.f};
#pragma unroll
    for (int i = 0; i < 4; i++)
#pragma unroll
        for (int j = 0; j < 4; j++) acc[i][j] = z;

    int arow = tid >> 2, ac = (tid & 3) * 8;  // 64 rows covered; +64 for second half
    const ushort* gA0 = A + (size_t)(m0 + arow) * lda + ac;
    const ushort* gA1 = A + (size_t)(m0 + arow + 64) * lda + ac;
    const ushort* gB0 = Bt + (size_t)(n0 + arow) * ldb + ac;
    const ushort* gB1 = Bt + (size_t)(n0 + arow + 64) * ldb + ac;

    for (int k0 = 0; k0 < K; k0 += 32) {
        uint4 va0 = *(const uint4*)gA0;
        uint4 va1 = *(const uint4*)gA1;
        uint4 vb0 = *(const uint4*)gB0;
        uint4 vb1 = *(const uint4*)gB1;
        gA0 += 32; gA1 += 32; gB0 += 32; gB1 += 32;
        __syncthreads();  // previous tile fully consumed
        *(uint4*)&As[arow * 32 + ac] = va0;
        *(uint4*)&As[(arow + 64) * 32 + ac] = va1;
        *(uint4*)&Bs[arow * 32 + ac] = vb0;
        *(uint4*)&Bs[(arow + 64) * 32 + ac] = vb1;
        __syncthreads();

        short8 af[4];
#pragma unroll
        for (int i = 0; i < 4; i++)
            af[i] = *(const short8*)&As[(wr + i * 16 + l15) * 32 + quad * 8];
#pragma unroll
        for (int j = 0; j < 4; j++) {
            short8 bf = *(const short8*)&Bs[(wc + j * 16 + l15) * 32 + quad * 8];
#pragma unroll
            for (int i = 0; i < 4; i++)
                acc[i][j] = __builtin_amdgcn_mfma_f32_16x16x32_bf16(af[i], bf, acc[i][j], 0, 0, 0);
        }
    }

    // epilogue: C row = (lane>>4)*4 + reg, col = lane&15 within each 16x16 tile
#pragma unroll
    for (int i = 0; i < 4; i++) {
        int row0 = m0 + wr + i * 16 + quad * 4;
#pragma unroll
        for (int j = 0; j < 4; j++) {
            int col = n0 + wc + j * 16 + l15;
#pragma unroll
            for (int r = 0; r < 4; r++) {
                float v = acc[i][j][r];
                if constexpr (sizeof(OutT) == 2)
                    C[(size_t)(row0 + r) * ldc + col] = (OutT)f2bf(v);
                else
                    C[(size_t)(row0 + r) * ldc + col] = v;
            }
        }
    }
}

// ---------------- RoPE in-place on Q and K slices of qkv ----------------
__global__ void rope_kernel(ushort* __restrict__ qkv, const float* __restrict__ cosb,
                            const float* __restrict__ sinb) {
    int t = blockIdx.x;
    ushort* row = qkv + (size_t)t * QKV_N;
    const float* cr = cosb + (size_t)t * D_HEAD;
    const float* sr = sinb + (size_t)t * D_HEAD;
    // 5120 bf16 (Q+K) = 40 slices of 128; 64 rotation pairs per slice
    for (int c = threadIdx.x; c < 2560; c += 256) {
        int slice = c >> 6, d = c & 63;
        int col = slice * 128 + d;
        float x0 = bf2f(row[col]), x1 = bf2f(row[col + 64]);
        float cs = cr[d], sn = sr[d];
        row[col] = f2bf(x0 * cs - x1 * sn);
        row[col + 64] = f2bf(x1 * cs + x0 * sn);
    }
}

// ---------------- flash-style causal GQA attention ----------------
// block = (q-tile of 64 rows, head). 4 waves, each owns a 16-row strip.
__global__ __launch_bounds__(256) void attn_kernel(const ushort* __restrict__ qkv,
                                                   ushort* __restrict__ attn) {
    __shared__ ushort Qs[64 * 132];   // stride 132 to break 256B conflicts
    __shared__ ushort Ks[64 * 132];
    __shared__ ushort Vt[128 * 68];   // V transposed [d][key], stride 68
    __shared__ ushort Ps[64 * 66];    // P round-trip (C-layout -> A-layout)

    int qt = blockIdx.x, h = blockIdx.y;
    int q0 = qt * 64;
    int tid = threadIdx.x, w = tid >> 6, lane = tid & 63, quad = lane >> 4, l15 = lane & 15;
    int kvh = h >> 2;  // GQA: jnp.repeat groups of 4
    const ushort* qbase = qkv + h * D_HEAD;
    const ushort* kbase = qkv + KOFF + kvh * D_HEAD;
    const ushort* vbase = qkv + VOFF + kvh * D_HEAD;

    // stage Q tile (64 x 128)
    {
        int r = tid >> 4, d0 = (tid & 15) * 8;
#pragma unroll
        for (int it = 0; it < 4; it++) {
            uint4 v = *(const uint4*)(qbase + (size_t)(q0 + r + it * 16) * QKV_N + d0);
            *(uint2*)&Qs[(r + it * 16) * 132 + d0] = make_uint2(v.x, v.y);
            *(uint2*)&Qs[(r + it * 16) * 132 + d0 + 4] = make_uint2(v.z, v.w);
        }
    }
    __syncthreads();
    // hoist Q A-frags: m = lane&15 within this wave's strip, k = ks*32 + quad*8 + j
    short8 qf[4];
#pragma unroll
    for (int ks = 0; ks < 4; ks++)
        qf[ks] = ld8(&Qs[(w * 16 + l15) * 132 + ks * 32 + quad * 8]);

    float m_i[4], l_i[4];
    floatx4 o[8];
    floatx4 z = {0.f, 0.f, 0.f, 0.f};
#pragma unroll
    for (int r = 0; r < 4; r++) { m_i[r] = -1e30f; l_i[r] = 0.f; }
#pragma unroll
    for (int j = 0; j < 8; j++) o[j] = z;

    const float scale = 0.08838834764831845f;  // D^-0.5

    for (int kb = 0; kb <= qt; kb++) {
        int k0 = kb * 64;
        __syncthreads();  // protect Ks/Vt from previous iteration's readers
        {   // stage K (row-major) and V (transposed)
            int r = tid >> 4, d0 = (tid & 15) * 8;
#pragma unroll
            for (int it = 0; it < 4; it++) {
                int rr = r + it * 16;
                uint4 kv = *(const uint4*)(kbase + (size_t)(k0 + rr) * QKV_N + d0);
                *(uint2*)&Ks[rr * 132 + d0] = make_uint2(kv.x, kv.y);
                *(uint2*)&Ks[rr * 132 + d0 + 4] = make_uint2(kv.z, kv.w);
                uint4 vv = *(const uint4*)(vbase + (size_t)(k0 + rr) * QKV_N + d0);
                ushort tmp[8];
                *(uint4*)tmp = vv;
#pragma unroll
                for (int e = 0; e < 8; e++) Vt[(d0 + e) * 68 + rr] = tmp[e];
            }
        }
        __syncthreads();

        // S = Q K^T  (each wave: 16 q-rows x 64 keys)
        floatx4 s[4];
#pragma unroll
        for (int jt = 0; jt < 4; jt++) s[jt] = z;
#pragma unroll
        for (int ks = 0; ks < 4; ks++) {
#pragma unroll
            for (int jt = 0; jt < 4; jt++) {
                short8 kf = ld8(&Ks[(jt * 16 + l15) * 132 + ks * 32 + quad * 8]);
                s[jt] = __builtin_amdgcn_mfma_f32_16x16x32_bf16(qf[ks], kf, s[jt], 0, 0, 0);
            }
        }

        // online softmax; C-layout row = quad*4 + r is identical for S and O,
        // so per-row stats live in registers (16 l15-lanes hold identical copies).
        bool diag = (kb == qt);
#pragma unroll
        for (int r = 0; r < 4; r++) {
            int grow = q0 + w * 16 + quad * 4 + r;
            float sv[4];
            float mx = -1e30f;
#pragma unroll
            for (int jt = 0; jt < 4; jt++) {
                float v = s[jt][r] * scale;
                if (diag && (k0 + jt * 16 + l15 > grow)) v = -1e30f;
                sv[jt] = v;
                mx = fmaxf(mx, v);
            }
#pragma unroll
            for (int mk = 1; mk <= 8; mk <<= 1) mx = fmaxf(mx, __shfl_xor(mx, mk));
            float nm = fmaxf(m_i[r], mx);
            float alpha = __expf(m_i[r] - nm);
            m_i[r] = nm;
            float rs = 0.f;
#pragma unroll
            for (int jt = 0; jt < 4; jt++) {
                float p = __expf(sv[jt] - nm);
                rs += p;
                Ps[(w * 16 + quad * 4 + r) * 66 + jt * 16 + l15] = f2bf(p);
            }
#pragma unroll
            for (int mk = 1; mk <= 8; mk <<= 1) rs += __shfl_xor(rs, mk);
            l_i[r] = l_i[r] * alpha + rs;
#pragma unroll
            for (int jt = 0; jt < 8; jt++) o[jt][r] *= alpha;
        }

        // O += P V  (Ps region is wave-private: no barrier needed, lgkmcnt handles RAW)
#pragma unroll
        for (int ks2 = 0; ks2 < 2; ks2++) {
            short8 pf = ld8_4(&Ps[(w * 16 + l15) * 66 + ks2 * 32 + quad * 8]);
#pragma unroll
            for (int jt = 0; jt < 8; jt++) {
                short8 vf = ld8(&Vt[(jt * 16 + l15) * 68 + ks2 * 32 + quad * 8]);
                o[jt] = __builtin_amdgcn_mfma_f32_16x16x32_bf16(pf, vf, o[jt], 0, 0, 0);
            }
        }
    }

    // epilogue: normalize and store bf16 attn output (T x 4096)
#pragma unroll
    for (int r = 0; r < 4; r++) {
        float inv = 1.f / l_i[r];
        int trow = q0 + w * 16 + quad * 4 + r;
        ushort* orow = attn + (size_t)trow * (HQ * D_HEAD) + h * D_HEAD;
#pragma unroll
        for (int jt = 0; jt < 8; jt++)
            orow[jt * 16 + l15] = f2bf(o[jt][r] * inv);
    }
}

// ---------------- launch ----------------
extern "C" void kernel_launch(void* const* d_in, const int* in_sizes, int n_in,
                              void* d_out, int out_size, void* d_ws, size_t ws_size,
                              hipStream_t stream) {
    const float* hidden = (const float*)d_in[0];
    // d_in[1] = position_ids (unused; cos/sin are precomputed)
    const float* cosb = (const float*)d_in[2];
    const float* sinb = (const float*)d_in[3];
    const float* Wq = (const float*)d_in[4];
    const float* Wk = (const float*)d_in[5];
    const float* Wv = (const float*)d_in[6];
    const float* Wo = (const float*)d_in[7];
    float* out = (float*)d_out;

    char* ws = (char*)d_ws;
    ushort* hiddenB = (ushort*)(ws);                          // 16 MB: T x HID bf16
    ushort* WqkvT   = (ushort*)(ws + (size_t)(16u << 20));    // 48 MB: [6144][4096] bf16
    ushort* WoT     = (ushort*)(ws + (size_t)(64u << 20));    // 32 MB: [4096][4096] bf16
    ushort* qkv     = (ushort*)(ws + (size_t)(96u << 20));    // 24 MB: T x 6144 bf16
    ushort* attnO   = (ushort*)(ws + (size_t)(120u << 20));   // 16 MB: T x 4096 bf16
    // total 136 MB

    cast_f32_bf16<<<8192, 256, 0, stream>>>(hidden, hiddenB, T_DIM * HID);
    transpose_cast<<<dim3(128, 128), 256, 0, stream>>>(Wq, WqkvT, HID, 4096);
    transpose_cast<<<dim3(32, 128), 256, 0, stream>>>(Wk, WqkvT + (size_t)4096 * HID, HID, 1024);
    transpose_cast<<<dim3(32, 128), 256, 0, stream>>>(Wv, WqkvT + (size_t)5120 * HID, HID, 1024);
    transpose_cast<<<dim3(128, 128), 256, 0, stream>>>(Wo, WoT, HID, 4096);

    // qkv = hidden @ [Wq|Wk|Wv]   (M=2048, N=6144, K=4096), bf16 out
    gemm_bt<ushort><<<dim3(48, 16), 256, 0, stream>>>(hiddenB, WqkvT, qkv,
                                                      HID, HID, HID, QKV_N);
    rope_kernel<<<T_DIM, 256, 0, stream>>>(qkv, cosb, sinb);
    attn_kernel<<<dim3(T_DIM / 64, HQ), 256, 0, stream>>>(qkv, attnO);
    // out = attnO @ Wo  (M=2048, N=4096, K=4096), fp32 out
    gemm_bt<float><<<dim3(32, 16), 256, 0, stream>>>(attnO, WoT, out,
                                                     HID, HID, HID, HID);
}

// Round 2
// 708.571 us; speedup vs baseline: 1.1514x; 1.1514x over previous
//
#include <hip/hip_runtime.h>
#include <hip/hip_bf16.h>
#include <cstdint>
#include <cstddef>

// Problem constants
#define T_DIM   2048
#define HID     4096
#define HQ      32
#define HKV     8
#define D_HEAD  128
#define QKV_N   6144   // 4096 Q + 1024 K + 1024 V
#define KOFF    4096
#define VOFF    5120

typedef __attribute__((ext_vector_type(8))) short short8;   // 8 bf16 (4 VGPRs)
typedef __attribute__((ext_vector_type(4))) float floatx4;  // MFMA C/D frag

__device__ __forceinline__ ushort f2bf(float f) {
    union { float f; uint u; } v; v.f = f;
    uint r = v.u + 0x7fffu + ((v.u >> 16) & 1u);  // RNE
    return (ushort)(r >> 16);
}
__device__ __forceinline__ float bf2f(ushort h) {
    union { uint u; float f; } v; v.u = ((uint)h) << 16; return v.f;
}
// 8 bf16 from 8B-aligned LDS
__device__ __forceinline__ short8 ld8(const ushort* p) {
    uint2 a = *(const uint2*)p, b = *(const uint2*)(p + 4);
    union { uint u[4]; short8 s; } x;
    x.u[0] = a.x; x.u[1] = a.y; x.u[2] = b.x; x.u[3] = b.y;
    return x.s;
}
// async global->LDS, 16B per lane. LDS dest must be wave-uniform + lane*16.
__device__ __forceinline__ void gld_lds16(const ushort* g, ushort* l) {
    __builtin_amdgcn_global_load_lds(
        (__attribute__((address_space(1))) void*)(g),
        (__attribute__((address_space(3))) void*)(l), 16, 0, 0);
}

// ---------------- elementwise cast fp32 -> bf16 ----------------
__global__ void cast_f32_bf16(const float* __restrict__ in, ushort* __restrict__ out, int n) {
    int i = (blockIdx.x * blockDim.x + threadIdx.x) * 4;
    if (i < n) {
        float4 v = *(const float4*)(in + i);
        ushort4 o;
        o.x = f2bf(v.x); o.y = f2bf(v.y); o.z = f2bf(v.z); o.w = f2bf(v.w);
        *(ushort4*)(out + i) = o;
    }
}

// ---------------- transpose + cast: W[K][N] fp32 -> Wt[N][K] bf16 ----------------
__global__ void transpose_cast(const float* __restrict__ W, ushort* __restrict__ Wt, int K, int N) {
    __shared__ float tile[32][33];
    int n0 = blockIdx.x * 32, k0 = blockIdx.y * 32;
    int tx = threadIdx.x & 31, ty = threadIdx.x >> 5;  // 32 x 8
#pragma unroll
    for (int i = 0; i < 4; i++) {
        int r = ty + i * 8;
        tile[r][tx] = W[(size_t)(k0 + r) * N + n0 + tx];
    }
    __syncthreads();
#pragma unroll
    for (int i = 0; i < 4; i++) {
        int r = ty + i * 8;
        Wt[(size_t)(n0 + r) * K + k0 + tx] = f2bf(tile[tx][r]);
    }
}

// ---------------- transpose V slice of qkv -> VtG[kvh][d][t] (t contiguous) ----------------
__global__ void transpose_v(const ushort* __restrict__ qkv, ushort* __restrict__ VtG) {
    __shared__ ushort tile[32][33];
    int t0 = blockIdx.x * 32, d0 = blockIdx.y * 32, kvh = blockIdx.z;
    int tx = threadIdx.x & 31, ty = threadIdx.x >> 5;  // 32 x 8
#pragma unroll
    for (int i = 0; i < 4; i++) {
        int t = t0 + ty + i * 8;
        tile[ty + i * 8][tx] = qkv[(size_t)t * QKV_N + VOFF + kvh * D_HEAD + d0 + tx];
    }
    __syncthreads();
#pragma unroll
    for (int i = 0; i < 4; i++) {
        int d = d0 + ty + i * 8;
        VtG[((size_t)kvh * D_HEAD + d) * T_DIM + t0 + tx] = tile[tx][ty + i * 8];
    }
}

// ---------------- bf16 MFMA GEMM: C[M][N] = A[M][K] * Bt[N][K]^T ----------------
// 128x128 tile, 4 waves (2x2 of 64x64), 16x16x32 MFMA, BK=32.
// Staging via global_load_lds width=16 (m97 structure): lds byte offset == tid*16.
template <typename OutT>
__global__ __launch_bounds__(256) void gemm_bt(const ushort* __restrict__ A,
                                               const ushort* __restrict__ Bt,
                                               OutT* __restrict__ C,
                                               int K, int lda, int ldb, int ldc) {
    __shared__ ushort As[128 * 32];
    __shared__ ushort Bs[128 * 32];
    int tid = threadIdx.x;
    int w = tid >> 6, lane = tid & 63, quad = lane >> 4, l15 = lane & 15;
    int wr = (w >> 1) * 64, wc = (w & 1) * 64;
    int m0 = blockIdx.y * 128, n0 = blockIdx.x * 128;

    floatx4 acc[4][4];
    floatx4 z = {0.f, 0.f, 0.f, 0.f};
#pragma unroll
    for (int i = 0; i < 4; i++)
#pragma unroll
        for (int j = 0; j < 4; j++) acc[i][j] = z;

    int arow = tid >> 2, ac = (tid & 3) * 8;  // lds ushort offset arow*32+ac == tid*8
    const ushort* gA0 = A + (size_t)(m0 + arow) * lda + ac;
    const ushort* gA1 = A + (size_t)(m0 + arow + 64) * lda + ac;
    const ushort* gB0 = Bt + (size_t)(n0 + arow) * ldb + ac;
    const ushort* gB1 = Bt + (size_t)(n0 + arow + 64) * ldb + ac;

    for (int k0 = 0; k0 < K; k0 += 32) {
        __syncthreads();  // previous tile fully consumed
        gld_lds16(gA0, &As[tid * 8]);
        gld_lds16(gA1, &As[64 * 32 + tid * 8]);
        gld_lds16(gB0, &Bs[tid * 8]);
        gld_lds16(gB1, &Bs[64 * 32 + tid * 8]);
        gA0 += 32; gA1 += 32; gB0 += 32; gB1 += 32;
        __syncthreads();  // vmcnt(0) drain -> data visible

        short8 af[4];
#pragma unroll
        for (int i = 0; i < 4; i++)
            af[i] = *(const short8*)&As[(wr + i * 16 + l15) * 32 + quad * 8];
#pragma unroll
        for (int j = 0; j < 4; j++) {
            short8 bf = *(const short8*)&Bs[(wc + j * 16 + l15) * 32 + quad * 8];
#pragma unroll
            for (int i = 0; i < 4; i++)
                acc[i][j] = __builtin_amdgcn_mfma_f32_16x16x32_bf16(af[i], bf, acc[i][j], 0, 0, 0);
        }
    }

    // epilogue: C row = (lane>>4)*4 + reg, col = lane&15 within each 16x16 tile
#pragma unroll
    for (int i = 0; i < 4; i++) {
        int row0 = m0 + wr + i * 16 + quad * 4;
#pragma unroll
        for (int j = 0; j < 4; j++) {
            int col = n0 + wc + j * 16 + l15;
#pragma unroll
            for (int r = 0; r < 4; r++) {
                float v = acc[i][j][r];
                if constexpr (sizeof(OutT) == 2)
                    C[(size_t)(row0 + r) * ldc + col] = (OutT)f2bf(v);
                else
                    C[(size_t)(row0 + r) * ldc + col] = v;
            }
        }
    }
}

// ---------------- RoPE in-place on Q and K slices of qkv ----------------
__global__ void rope_kernel(ushort* __restrict__ qkv, const float* __restrict__ cosb,
                            const float* __restrict__ sinb) {
    int t = blockIdx.x;
    ushort* row = qkv + (size_t)t * QKV_N;
    const float* cr = cosb + (size_t)t * D_HEAD;
    const float* sr = sinb + (size_t)t * D_HEAD;
    for (int c = threadIdx.x; c < 2560; c += 256) {
        int slice = c >> 6, d = c & 63;
        int col = slice * 128 + d;
        float x0 = bf2f(row[col]), x1 = bf2f(row[col + 64]);
        float cs = cr[d], sn = sr[d];
        row[col] = f2bf(x0 * cs - x1 * sn);
        row[col + 64] = f2bf(x1 * cs + x0 * sn);
    }
}

// ---------------- flash-style causal GQA attention ----------------
// block = (q-tile of 64 rows, head). 4 waves, each owns a 16-row strip.
// LDS: Qs/Ks stride 136 (bank stride 4 -> 2-way max), Vt stride 72, Ps stride 68.
// Ps overlays Qs (Q hoisted to regs before loop). Total 53248 B -> 3 blocks/CU.
#define QS_STRIDE 136
#define VT_STRIDE 72
#define PS_STRIDE 68

__global__ __launch_bounds__(256) void attn_kernel(const ushort* __restrict__ qkv,
                                                   const ushort* __restrict__ VtG,
                                                   ushort* __restrict__ attn) {
    __shared__ ushort Qs[64 * QS_STRIDE];   // reused as Ps[64*PS_STRIDE] after hoist
    __shared__ ushort Ks[64 * QS_STRIDE];
    __shared__ ushort Vt[128 * VT_STRIDE];
    ushort* Ps = Qs;

    int qt = (gridDim.x - 1) - blockIdx.x;  // heavy tiles dispatch first
    int h = blockIdx.y;
    int q0 = qt * 64;
    int tid = threadIdx.x, w = tid >> 6, lane = tid & 63, quad = lane >> 4, l15 = lane & 15;
    int kvh = h >> 2;  // GQA group of 4
    const ushort* qbase = qkv + h * D_HEAD;
    const ushort* kbase = qkv + KOFF + kvh * D_HEAD;
    const ushort* vtb = VtG + (size_t)kvh * D_HEAD * T_DIM;

    // stage Q tile (64 x 128): thread -> row tid>>2, 64B chunk (tid&3)*32
    {
        int r = tid >> 2, c0 = (tid & 3) * 32;
        const ushort* src = qbase + (size_t)(q0 + r) * QKV_N + c0;
#pragma unroll
        for (int i = 0; i < 2; i++) {
            *(uint4*)&Qs[r * QS_STRIDE + c0 + i * 16] = *(const uint4*)(src + i * 16);
            *(uint4*)&Qs[r * QS_STRIDE + c0 + i * 16 + 8] = *(const uint4*)(src + i * 16 + 8);
        }
    }
    __syncthreads();
    // hoist Q A-frags: m = l15 within wave strip, k = ks*32 + quad*8 + j
    short8 qf[4];
#pragma unroll
    for (int ks = 0; ks < 4; ks++)
        qf[ks] = ld8(&Qs[(w * 16 + l15) * QS_STRIDE + ks * 32 + quad * 8]);

    float m_i[4], l_i[4];
    floatx4 o[8];
    floatx4 z = {0.f, 0.f, 0.f, 0.f};
#pragma unroll
    for (int r = 0; r < 4; r++) { m_i[r] = -1e30f; l_i[r] = 0.f; }
#pragma unroll
    for (int j = 0; j < 8; j++) o[j] = z;

    const float scale_l2e = 0.08838834764831845f * 1.4426950408889634f;  // D^-0.5 * log2(e)

    for (int kb = 0; kb <= qt; kb++) {
        int k0 = kb * 64;
        __syncthreads();  // Ks/Vt consumed by all waves (incl. prev PV reads)
        {   // stage K (64x128 row-major) and Vt (128 d-rows x 64 keys)
            int r = tid >> 2, c0 = (tid & 3) * 32;
            const ushort* ksrc = kbase + (size_t)(k0 + r) * QKV_N + c0;
#pragma unroll
            for (int i = 0; i < 2; i++) {
                *(uint4*)&Ks[r * QS_STRIDE + c0 + i * 16] = *(const uint4*)(ksrc + i * 16);
                *(uint4*)&Ks[r * QS_STRIDE + c0 + i * 16 + 8] = *(const uint4*)(ksrc + i * 16 + 8);
            }
            int d = tid >> 1, vc0 = (tid & 1) * 32;
            const ushort* vsrc = vtb + (size_t)d * T_DIM + k0 + vc0;
#pragma unroll
            for (int i = 0; i < 2; i++) {
                *(uint4*)&Vt[d * VT_STRIDE + vc0 + i * 16] = *(const uint4*)(vsrc + i * 16);
                *(uint4*)&Vt[d * VT_STRIDE + vc0 + i * 16 + 8] = *(const uint4*)(vsrc + i * 16 + 8);
            }
        }
        __syncthreads();

        // S = Q K^T  (each wave: 16 q-rows x 64 keys)
        floatx4 s[4];
#pragma unroll
        for (int jt = 0; jt < 4; jt++) s[jt] = z;
#pragma unroll
        for (int ks = 0; ks < 4; ks++) {
#pragma unroll
            for (int jt = 0; jt < 4; jt++) {
                short8 kf = ld8(&Ks[(jt * 16 + l15) * QS_STRIDE + ks * 32 + quad * 8]);
                s[jt] = __builtin_amdgcn_mfma_f32_16x16x32_bf16(qf[ks], kf, s[jt], 0, 0, 0);
            }
        }

        // online softmax in exp2 domain; C-layout row = quad*4 + r matches O rows.
        bool diag = (kb == qt);
#pragma unroll
        for (int r = 0; r < 4; r++) {
            int grow = q0 + w * 16 + quad * 4 + r;
            float sv[4];
            float mx = -1e30f;
#pragma unroll
            for (int jt = 0; jt < 4; jt++) {
                float v = s[jt][r] * scale_l2e;
                if (diag && (k0 + jt * 16 + l15 > grow)) v = -1e30f;
                sv[jt] = v;
                mx = fmaxf(mx, v);
            }
#pragma unroll
            for (int mk = 1; mk <= 8; mk <<= 1) mx = fmaxf(mx, __shfl_xor(mx, mk));
            float nm = fmaxf(m_i[r], mx);
            float alpha = exp2f(m_i[r] - nm);
            m_i[r] = nm;
            float rs = 0.f;
#pragma unroll
            for (int jt = 0; jt < 4; jt++) {
                float p = exp2f(sv[jt] - nm);
                rs += p;
                Ps[(w * 16 + quad * 4 + r) * PS_STRIDE + jt * 16 + l15] = f2bf(p);
            }
#pragma unroll
            for (int mk = 1; mk <= 8; mk <<= 1) rs += __shfl_xor(rs, mk);
            l_i[r] = l_i[r] * alpha + rs;
#pragma unroll
            for (int jt = 0; jt < 8; jt++) o[jt][r] *= alpha;
        }

        // O += P V (Ps rows are wave-private; lgkmcnt handles the RAW)
#pragma unroll
        for (int ks2 = 0; ks2 < 2; ks2++) {
            short8 pf = ld8(&Ps[(w * 16 + l15) * PS_STRIDE + ks2 * 32 + quad * 8]);
#pragma unroll
            for (int jt = 0; jt < 8; jt++) {
                short8 vf = ld8(&Vt[(jt * 16 + l15) * VT_STRIDE + ks2 * 32 + quad * 8]);
                o[jt] = __builtin_amdgcn_mfma_f32_16x16x32_bf16(pf, vf, o[jt], 0, 0, 0);
            }
        }
    }

    // epilogue: normalize and store bf16 attn output (T x 4096)
#pragma unroll
    for (int r = 0; r < 4; r++) {
        float inv = 1.f / l_i[r];
        int trow = q0 + w * 16 + quad * 4 + r;
        ushort* orow = attn + (size_t)trow * (HQ * D_HEAD) + h * D_HEAD;
#pragma unroll
        for (int jt = 0; jt < 8; jt++)
            orow[jt * 16 + l15] = f2bf(o[jt][r] * inv);
    }
}

// ---------------- launch ----------------
extern "C" void kernel_launch(void* const* d_in, const int* in_sizes, int n_in,
                              void* d_out, int out_size, void* d_ws, size_t ws_size,
                              hipStream_t stream) {
    const float* hidden = (const float*)d_in[0];
    const float* cosb = (const float*)d_in[2];
    const float* sinb = (const float*)d_in[3];
    const float* Wq = (const float*)d_in[4];
    const float* Wk = (const float*)d_in[5];
    const float* Wv = (const float*)d_in[6];
    const float* Wo = (const float*)d_in[7];
    float* out = (float*)d_out;

    char* ws = (char*)d_ws;
    ushort* hiddenB = (ushort*)(ws);                          // 16 MB: T x HID bf16
    ushort* WqkvT   = (ushort*)(ws + (size_t)(16u << 20));    // 48 MB: [6144][4096] bf16
    ushort* WoT     = (ushort*)(ws + (size_t)(64u << 20));    // 32 MB: [4096][4096] bf16
    ushort* qkv     = (ushort*)(ws + (size_t)(96u << 20));    // 24 MB: T x 6144 bf16
    ushort* attnO   = (ushort*)(ws + (size_t)(120u << 20));   // 16 MB: T x 4096 bf16
    ushort* VtG     = (ushort*)(ws + (size_t)(136u << 20));   // 4 MB: [HKV][128][2048] bf16
    // total 140 MB

    cast_f32_bf16<<<8192, 256, 0, stream>>>(hidden, hiddenB, T_DIM * HID);
    transpose_cast<<<dim3(128, 128), 256, 0, stream>>>(Wq, WqkvT, HID, 4096);
    transpose_cast<<<dim3(32, 128), 256, 0, stream>>>(Wk, WqkvT + (size_t)4096 * HID, HID, 1024);
    transpose_cast<<<dim3(32, 128), 256, 0, stream>>>(Wv, WqkvT + (size_t)5120 * HID, HID, 1024);
    transpose_cast<<<dim3(128, 128), 256, 0, stream>>>(Wo, WoT, HID, 4096);

    // qkv = hidden @ [Wq|Wk|Wv]   (M=2048, N=6144, K=4096), bf16 out
    gemm_bt<ushort><<<dim3(48, 16), 256, 0, stream>>>(hiddenB, WqkvT, qkv,
                                                      HID, HID, HID, QKV_N);
    rope_kernel<<<T_DIM, 256, 0, stream>>>(qkv, cosb, sinb);
    transpose_v<<<dim3(64, 4, 8), 256, 0, stream>>>(qkv, VtG);
    attn_kernel<<<dim3(T_DIM / 64, HQ), 256, 0, stream>>>(qkv, VtG, attnO);
    // out = attnO @ Wo  (M=2048, N=4096, K=4096), fp32 out
    gemm_bt<float><<<dim3(32, 16), 256, 0, stream>>>(attnO, WoT, out,
                                                     HID, HID, HID, HID);
}